// Round 12
// baseline (4370.894 us; speedup 1.0000x reference)
//
#include <hip/hip_runtime.h>

typedef __bf16 bf16;
typedef bf16 bf16x2 __attribute__((ext_vector_type(2)));
typedef bf16 bf16x4 __attribute__((ext_vector_type(4)));
typedef bf16 bf16x8 __attribute__((ext_vector_type(8)));
typedef float f32x4 __attribute__((ext_vector_type(4)));

#define DEVFN __device__ __forceinline__

constexpr int cV = 50000, cE = 256, cH = 512, cM = 100, cH2 = 256;
constexpr int cB = 64, cS = 400, cT = 25, cEOS = 2;
constexpr int cSB = cS * cB;          // 25600
constexpr int cG2 = 3 * cH2;          // 768
constexpr int cGP = 772;              // gi LDS row pad
constexpr int cKcat = 1280;           // [c(512) | wemb(256) | h(512)]
constexpr int cN4 = 2048;             // interleaved r,z,inn,hn rows
constexpr int cNTV = (cV + 63) / 64;  // 782
constexpr int cTD = cT - 1;           // 24 decode steps
constexpr int cVT = cV / 16;          // 3125 Wv 16-row tiles

// concatenated bf16 weight cache offsets (elements)
constexpr size_t OFF_WV = 0;
constexpr size_t N_WV = (size_t)cV * cH;
constexpr size_t OFF_WIHF = OFF_WV + N_WV;
constexpr size_t N_WIH = (size_t)cG2 * cE;
constexpr size_t OFF_WHHF = OFF_WIHF + N_WIH;
constexpr size_t N_WHH = (size_t)cG2 * cH2;
constexpr size_t OFF_WIHB = OFF_WHHF + N_WHH;
constexpr size_t OFF_WHHB = OFF_WIHB + N_WIH;
constexpr size_t OFF_W1 = OFF_WHHB + N_WHH;
constexpr size_t N_WSQ = (size_t)cH * cH;
constexpr size_t OFF_W2 = OFF_W1 + N_WSQ;
constexpr size_t OFF_WE = OFF_W2 + N_WSQ;
constexpr size_t N_WE = (size_t)cM * cH;
constexpr size_t TOT_W = OFF_WE + N_WE;

// merged prep grid ranges (round-10 proven)
constexpr int NB_CVT = (int)(TOT_W / 4 / 256);
constexpr int NB_WP = cN4 * cKcat / 256;
constexpr int NB_GATHER = cSB * cE / 256;
constexpr int NB_PREP = NB_CVT + NB_WP + NB_GATHER;

struct GArgs {
  const bf16* A; const bf16* Bw; const float* bias;
  float* outF; bf16* outBf;
  const float* auxF; const bf16* auxBf;
  int M, N, K, ldo;
};

DEVFN float sigm(float x) { return 1.f / (1.f + __expf(-x)); }
DEVFN float tanh_f(float x) {
  float e2 = __expf(2.f * x);
  return 1.f - 2.f / (e2 + 1.f);
}

DEVFN void gload_lds16(const void* g, void* l) {
  __builtin_amdgcn_global_load_lds(
      (const __attribute__((address_space(1))) void*)g,
      (__attribute__((address_space(3))) void*)l, 16, 0, 0);
}

// ---------------- generic 64x64-per-wave MFMA GEMM: C = A(MxK) * B(NxK)^T ----------------
template <int EPI>
__global__ __launch_bounds__(256) void gemm64_k(GArgs g) {
  const int tid = threadIdx.x;
  const int w = blockIdx.x * 4 + (tid >> 6);
  const int tM = g.M >> 6;
  const int tN = (g.N + 63) >> 6;
  if (w >= tM * tN) return;
  const int im = w % tM, in = w / tM;
  const int m0 = im << 6, n0 = in << 6;
  const int lane = tid & 63, lr = lane & 15, lh = lane >> 4;

  f32x4 acc[4][4];
#pragma unroll
  for (int i = 0; i < 4; ++i)
#pragma unroll
    for (int j = 0; j < 4; ++j)
#pragma unroll
      for (int r = 0; r < 4; ++r) acc[i][j][r] = 0.f;

  bf16x8 bz;
#pragma unroll
  for (int q = 0; q < 8; ++q) bz[q] = (bf16)0.f;

  const int K = g.K;
#pragma unroll 2
  for (int k0 = 0; k0 < K; k0 += 32) {
    bf16x8 av[4], bw[4];
#pragma unroll
    for (int mt = 0; mt < 4; ++mt)
      av[mt] = *(const bf16x8*)(g.A + (size_t)(m0 + mt * 16 + lr) * K + k0 + lh * 8);
#pragma unroll
    for (int nt = 0; nt < 4; ++nt) {
      int row = n0 + nt * 16 + lr;
      bw[nt] = (row < g.N) ? *(const bf16x8*)(g.Bw + (size_t)row * K + k0 + lh * 8) : bz;
    }
#pragma unroll
    for (int mt = 0; mt < 4; ++mt)
#pragma unroll
      for (int nt = 0; nt < 4; ++nt)
        acc[mt][nt] = __builtin_amdgcn_mfma_f32_16x16x32_bf16(av[mt], bw[nt], acc[mt][nt], 0, 0, 0);
  }

#pragma unroll
  for (int mt = 0; mt < 4; ++mt) {
#pragma unroll
    for (int nt = 0; nt < 4; ++nt) {
      const int n = n0 + nt * 16 + lr;
      if (n < g.N) {
        const float bia = g.bias[n];
#pragma unroll
        for (int r = 0; r < 4; ++r) {
          const int m = m0 + mt * 16 + lh * 4 + r;
          float v = acc[mt][nt][r] + bia;
          if constexpr (EPI == 0) {
            g.outF[(size_t)m * g.ldo + n] = v;
          } else {  // EPI==1: sgate epilogue
            float sg = sigm(v + g.auxF[(size_t)(m & 63) * g.ldo + n]);
            float st = (float)g.auxBf[(size_t)m * g.ldo + n];
            g.outBf[(size_t)m * g.ldo + n] = (bf16)(sg * st);
          }
        }
      }
    }
  }
}

// ---------------- merged prep: cvt8(Wv swizzled) + build_wp + gather (round-10) ----------------
__global__ void prep_k(const float* __restrict__ wv, const float* __restrict__ wihf,
                       const float* __restrict__ whhf, const float* __restrict__ wihb,
                       const float* __restrict__ whhb, const float* __restrict__ w1,
                       const float* __restrict__ w2, const float* __restrict__ we,
                       bf16* __restrict__ dst,
                       const float* __restrict__ Wih_c, const float* __restrict__ Whh_c,
                       const float* __restrict__ bih_c, const float* __restrict__ bhh_c,
                       bf16* __restrict__ Wp, float* __restrict__ bp,
                       const int* __restrict__ src, const float* __restrict__ emb,
                       bf16* __restrict__ embeds) {
  const int blk = blockIdx.x, tid = threadIdx.x;

  if (blk < NB_CVT) {
    size_t i = ((size_t)blk * 256 + tid) * 4;
    if (i >= TOT_W) return;
    if (i < OFF_WIHF) {  // Wv, fragment-swizzled
      float4 v = *(const float4*)(wv + i);
      size_t row = i >> 9, col = i & 511;
      size_t tile = row >> 4, lr = row & 15, kc = col >> 5, lh = (col >> 3) & 3, e = col & 7;
      size_t d = ((tile * 16 + kc) * 64 + lr * 4 + lh) * 8 + e;
      bf16x4 o;
      o[0] = (bf16)v.x; o[1] = (bf16)v.y; o[2] = (bf16)v.z; o[3] = (bf16)v.w;
      *(bf16x4*)(dst + d) = o;
      return;
    }
    const float* s;
    size_t off;
    if (i < OFF_WHHF) { s = wihf; off = OFF_WIHF; }
    else if (i < OFF_WIHB) { s = whhf; off = OFF_WHHF; }
    else if (i < OFF_WHHB) { s = wihb; off = OFF_WIHB; }
    else if (i < OFF_W1) { s = whhb; off = OFF_WHHB; }
    else if (i < OFF_W2) { s = w1; off = OFF_W1; }
    else if (i < OFF_WE) { s = w2; off = OFF_W2; }
    else { s = we; off = OFF_WE; }
    float4 v = *(const float4*)(s + (i - off));
    bf16x4 o;
    o[0] = (bf16)v.x; o[1] = (bf16)v.y; o[2] = (bf16)v.z; o[3] = (bf16)v.w;
    *(bf16x4*)(dst + i) = o;
    return;
  }
  if (blk < NB_CVT + NB_WP) {
    int i = (blk - NB_CVT) * 256 + tid;
    int j = i / cKcat, c = i % cKcat;
    int bi = j >> 6, gg = (j >> 4) & 3, idx = j & 15;
    int u = bi * 16 + idx;
    float v;
    if (gg == 0) v = (c < 768) ? Wih_c[(size_t)u * 768 + c] : Whh_c[(size_t)u * 512 + (c - 768)];
    else if (gg == 1) v = (c < 768) ? Wih_c[(size_t)(512 + u) * 768 + c] : Whh_c[(size_t)(512 + u) * 512 + (c - 768)];
    else if (gg == 2) v = (c < 768) ? Wih_c[(size_t)(1024 + u) * 768 + c] : 0.f;
    else v = (c < 768) ? 0.f : Whh_c[(size_t)(1024 + u) * 512 + (c - 768)];
    {
      size_t tile = (size_t)j >> 4, lr = j & 15, kc = c >> 5, lh = (c >> 3) & 3, e = c & 7;
      Wp[((tile * 40 + kc) * 64 + lr * 4 + lh) * 8 + e] = (bf16)v;
    }
    if (c == 0) {
      float bb;
      if (gg == 0) bb = bih_c[u] + bhh_c[u];
      else if (gg == 1) bb = bih_c[512 + u] + bhh_c[512 + u];
      else if (gg == 2) bb = bih_c[1024 + u];
      else bb = bhh_c[1024 + u];
      bp[j] = bb;
    }
    return;
  }
  {
    int i = (blk - NB_CVT - NB_WP) * 256 + tid;  // over S*B*E
    int e = i & 255;
    int sb = i >> 8;
    int s = sb >> 6, b = sb & 63;
    int tok = src[b * cS + s];
    embeds[i] = (bf16)emb[(size_t)tok * cE + e];
  }
}

// ---------------- both gi GEMMs in one launch ----------------
__global__ __launch_bounds__(256) void gi2_k(const bf16* __restrict__ embeds,
                                             const bf16* __restrict__ WihF,
                                             const float* __restrict__ bihF,
                                             float* __restrict__ giF,
                                             const bf16* __restrict__ WihB,
                                             const float* __restrict__ bihB,
                                             float* __restrict__ giB) {
  int blk = blockIdx.x;
  const bf16* Bw;
  const float* bias;
  float* outF;
  if (blk < 1200) { Bw = WihF; bias = bihF; outF = giF; }
  else { blk -= 1200; Bw = WihB; bias = bihB; outF = giB; }
  const int tid = threadIdx.x;
  const int w = blk * 4 + (tid >> 6);
  const int im = w % 400, in = w / 400;
  const int m0 = im << 6, n0 = in << 6;
  const int lane = tid & 63, lr = lane & 15, lh = lane >> 4;

  f32x4 acc[4][4];
#pragma unroll
  for (int i = 0; i < 4; ++i)
#pragma unroll
    for (int j = 0; j < 4; ++j)
#pragma unroll
      for (int r = 0; r < 4; ++r) acc[i][j][r] = 0.f;

#pragma unroll 2
  for (int k0 = 0; k0 < cE; k0 += 32) {
    bf16x8 av[4], bw[4];
#pragma unroll
    for (int mt = 0; mt < 4; ++mt)
      av[mt] = *(const bf16x8*)(embeds + (size_t)(m0 + mt * 16 + lr) * cE + k0 + lh * 8);
#pragma unroll
    for (int nt = 0; nt < 4; ++nt)
      bw[nt] = *(const bf16x8*)(Bw + (size_t)(n0 + nt * 16 + lr) * cE + k0 + lh * 8);
#pragma unroll
    for (int mt = 0; mt < 4; ++mt)
#pragma unroll
      for (int nt = 0; nt < 4; ++nt)
        acc[mt][nt] = __builtin_amdgcn_mfma_f32_16x16x32_bf16(av[mt], bw[nt], acc[mt][nt], 0, 0, 0);
  }
#pragma unroll
  for (int mt = 0; mt < 4; ++mt)
#pragma unroll
    for (int nt = 0; nt < 4; ++nt) {
      const int n = n0 + nt * 16 + lr;
      const float bia = bias[n];
#pragma unroll
      for (int r = 0; r < 4; ++r) {
        const int m = m0 + mt * 16 + lh * 4 + r;
        outF[(size_t)m * cG2 + n] = acc[mt][nt][r] + bia;
      }
    }
}

// ---------------- encoder GRU v6: 16 blocks (2 dirs x 8 batch-chunks of 8) ----------------
// Same r3 schedule (LDS gi prefetch 1-ahead, 1 barrier/step); per-CU LDS/VALU
// traffic halves. hs rows 8-15 stay zero (MFMA A-rows beyond the 8 batches).
__global__ __launch_bounds__(512, 1) void enc_rnn_k(
    const bf16* __restrict__ WhhF, const bf16* __restrict__ WhhB,
    const float* __restrict__ giF, const float* __restrict__ giB,
    const float* __restrict__ bhhF, const float* __restrict__ bhhB,
    bf16* __restrict__ hdec0_bf, float* __restrict__ hdec0_f,
    bf16* __restrict__ states) {
  const int blk = blockIdx.x;
  const int dir = blk >> 3;
  const int bc = blk & 7;  // batches [bc*8, bc*8+8)
  const bf16* Whh = dir ? WhhB : WhhF;
  const float* gi = dir ? giB : giF;
  const float* bhh = dir ? bhhB : bhhF;

  const int tid = threadIdx.x;
  const int lane = tid & 63, w = tid >> 6;
  const int lr = lane & 15, lh = lane >> 4;
  const int u0 = w * 32;

  bf16x8 Bf[6][8];
  float bh[6];
#pragma unroll
  for (int gg = 0; gg < 3; ++gg)
#pragma unroll
    for (int ut = 0; ut < 2; ++ut) {
      int nbase = gg * 256 + u0 + ut * 16;
#pragma unroll
      for (int kf = 0; kf < 8; ++kf)
        Bf[gg * 2 + ut][kf] = *(const bf16x8*)(Whh + (size_t)(nbase + lr) * 256 + kf * 32 + lh * 8);
      bh[gg * 2 + ut] = bhh[nbase + lr];
    }

  __shared__ float gilds[2][8][cGP];   // 49.4 KB
  __shared__ bf16 hs[2][16][264];      // rows 8-15 permanently zero

  auto prefetch = [&](int t2) {
    if (t2 >= cS || w >= 4) return;
    const int s2 = dir ? (cS - 1 - t2) : t2;
    const int buf = t2 & 1;
#pragma unroll
    for (int rr2 = 0; rr2 < 2; ++rr2) {
      const int row = w * 2 + rr2;  // 0..7
      const char* srcb = (const char*)(gi + ((size_t)s2 * cB + bc * 8 + row) * cG2);
      char* dstb = (char*)&gilds[buf][row][0];
#pragma unroll
      for (int c = 0; c < 3; ++c)
        gload_lds16(srcb + c * 1024 + lane * 16, dstb + c * 1024);
    }
  };

  float hreg[2][4];
#pragma unroll
  for (int ut = 0; ut < 2; ++ut)
#pragma unroll
    for (int r = 0; r < 4; ++r) hreg[ut][r] = 0.f;

  prefetch(0);
  for (int i = tid; i < 2 * 16 * 264; i += 512) ((bf16*)hs)[i] = (bf16)0.f;
  __syncthreads();

  for (int t = 0; t < cS; ++t) {
    const int buf = t & 1, nbuf = buf ^ 1;
    prefetch(t + 1);

    bf16x8 av[8];
#pragma unroll
    for (int kf = 0; kf < 8; ++kf)
      av[kf] = *(const bf16x8*)(&hs[buf][lr][kf * 32 + lh * 8]);

    float gir[2][4], giz[2][4], gin[2][4];
#pragma unroll
    for (int ut = 0; ut < 2; ++ut) {
      const int u = u0 + ut * 16 + lr;
#pragma unroll
      for (int r = 0; r < 4; ++r) {
        const int b = lh * 4 + r;
        if (b < 8) {
          gir[ut][r] = gilds[buf][b][u];
          giz[ut][r] = gilds[buf][b][256 + u];
          gin[ut][r] = gilds[buf][b][512 + u];
        } else {
          gir[ut][r] = 0.f; giz[ut][r] = 0.f; gin[ut][r] = 0.f;
        }
      }
    }

    f32x4 acc[6];
#pragma unroll
    for (int j = 0; j < 6; ++j)
#pragma unroll
      for (int r = 0; r < 4; ++r) acc[j][r] = 0.f;

#pragma unroll
    for (int kf = 0; kf < 8; ++kf)
#pragma unroll
      for (int nt = 0; nt < 6; ++nt)
        acc[nt] = __builtin_amdgcn_mfma_f32_16x16x32_bf16(av[kf], Bf[nt][kf], acc[nt], 0, 0, 0);

#pragma unroll
    for (int ut = 0; ut < 2; ++ut) {
      const int u = u0 + ut * 16 + lr;
#pragma unroll
      for (int r = 0; r < 4; ++r) {
        const int b = lh * 4 + r;
        if (b < 8) {
          float rr = sigm(gir[ut][r] + acc[ut][r] + bh[ut]);
          float zz = sigm(giz[ut][r] + acc[2 + ut][r] + bh[2 + ut]);
          float nn = tanh_f(gin[ut][r] + rr * (acc[4 + ut][r] + bh[4 + ut]));
          float hnew = (1.f - zz) * nn + zz * hreg[ut][r];
          hreg[ut][r] = hnew;
          hs[nbuf][b][u] = (bf16)hnew;
        }
      }
    }

    __syncthreads();

    if (tid < 256) {  // coalesced states store (8 rows x 32 bf16x8 chunks)
      const int s_src = dir ? (cS - 1 - t) : t;
      const int row = tid >> 5, c8 = tid & 31;
      bf16x8 v = *(const bf16x8*)(&hs[nbuf][row][c8 * 8]);
      *(bf16x8*)(states + ((size_t)s_src * cB + bc * 8 + row) * cH + dir * 256 + c8 * 8) = v;
    }
  }

#pragma unroll
  for (int ut = 0; ut < 2; ++ut)
#pragma unroll
    for (int r = 0; r < 4; ++r) {
      const int brow = lh * 4 + r;
      if (brow < 8) {
        const int b = bc * 8 + brow;
        const int col = dir * 256 + u0 + ut * 16 + lr;
        hdec0_f[(size_t)b * cH + col] = hreg[ut][r];
        hdec0_bf[(size_t)b * cH + col] = (bf16)hreg[ut][r];
      }
    }
}

// ---------------- encproj(transposed) + statesg transpose, one launch ----------------
__global__ __launch_bounds__(256) void projtransp_k(const bf16* __restrict__ statesg,
                                                    const bf16* __restrict__ We_b,
                                                    const float* __restrict__ be,
                                                    float* __restrict__ epT,
                                                    bf16* __restrict__ sgT) {
  __shared__ bf16 tile[64][520];
  const int tid = threadIdx.x;
  if (blockIdx.x < 200) {
    const int w = blockIdx.x * 4 + (tid >> 6);
    const int im = w % 400, in = w / 400;
    const int m0 = im << 6, n0 = in << 6;
    const int lane = tid & 63, lr = lane & 15, lh = lane >> 4;
    f32x4 acc[4][4];
#pragma unroll
    for (int i = 0; i < 4; ++i)
#pragma unroll
      for (int j = 0; j < 4; ++j)
#pragma unroll
        for (int r = 0; r < 4; ++r) acc[i][j][r] = 0.f;
    bf16x8 bz;
#pragma unroll
    for (int q = 0; q < 8; ++q) bz[q] = (bf16)0.f;
#pragma unroll 2
    for (int k0 = 0; k0 < cH; k0 += 32) {
      bf16x8 av[4], bw[4];
#pragma unroll
      for (int mt = 0; mt < 4; ++mt)
        av[mt] = *(const bf16x8*)(statesg + (size_t)(m0 + mt * 16 + lr) * cH + k0 + lh * 8);
#pragma unroll
      for (int nt = 0; nt < 4; ++nt) {
        int row = n0 + nt * 16 + lr;
        bw[nt] = (row < cM) ? *(const bf16x8*)(We_b + (size_t)row * cH + k0 + lh * 8) : bz;
      }
#pragma unroll
      for (int mt = 0; mt < 4; ++mt)
#pragma unroll
        for (int nt = 0; nt < 4; ++nt)
          acc[mt][nt] = __builtin_amdgcn_mfma_f32_16x16x32_bf16(av[mt], bw[nt], acc[mt][nt], 0, 0, 0);
    }
#pragma unroll
    for (int mt = 0; mt < 4; ++mt)
#pragma unroll
      for (int nt = 0; nt < 4; ++nt) {
        const int n = n0 + nt * 16 + lr;
        if (n < cM) {
          const float bia = be[n];
#pragma unroll
          for (int r = 0; r < 4; ++r) {
            const int m = m0 + mt * 16 + lh * 4 + r;
            const int bb = m & 63, s = m >> 6;
            epT[((size_t)bb * cM + n) * cS + s] = acc[mt][nt][r] + bia;
          }
        }
      }
    return;
  }
  // transpose: statesg[s][b][k] -> sgT[b][k][s]
  const int b = blockIdx.x - 200;
  for (int s0 = 0; s0 < cS; s0 += 64) {
    __syncthreads();
    for (int c = tid; c < 64 * 64; c += 256) {
      int row = c >> 6, col = c & 63;
      *(bf16x8*)(&tile[row][col * 8]) =
          *(const bf16x8*)(statesg + ((size_t)(s0 + row) * cB + b) * cH + col * 8);
    }
    __syncthreads();
    for (int c = tid; c < 512 * 8; c += 256) {
      int k = c >> 3, sc = c & 7;
      bf16x8 v;
#pragma unroll
      for (int j = 0; j < 8; ++j) v[j] = tile[sc * 8 + j][k];
      *(bf16x8*)(sgT + ((size_t)b * cH + k) * cS + s0 + sc * 8) = v;
    }
  }
}

// ---------------- decoder attention: 64 blocks x 512 threads (round-10 proven) ----------------
__global__ __launch_bounds__(512) void attn_k(
    const bf16* __restrict__ hin, const float* __restrict__ Wd, const float* __restrict__ bd,
    const float* __restrict__ Wo, const float* __restrict__ bo,
    const float* __restrict__ epT, const bf16* __restrict__ sgT,
    const float* __restrict__ emb, const int* __restrict__ trg, int t,
    bf16* __restrict__ xh) {
  const int b = blockIdx.x, tid = threadIdx.x;
  const int lane = tid & 63, wid = tid >> 6;  // 8 waves
  __shared__ float hsh[512];
  __shared__ float dsh[100];
  __shared__ float esh[400];
  __shared__ float red[32];
  __shared__ float wos[100];

  if (tid < 100) wos[tid] = Wo[tid];
  hsh[tid] = (float)hin[b * 512 + tid];
  __syncthreads();

  // dsh[j] = Wd[j].h + bd[j]; 8 waves strided over j
  for (int j = wid; j < 100; j += 8) {
    const float* wr = Wd + (size_t)j * 512 + lane * 8;
    float a = 0.f;
#pragma unroll
    for (int q = 0; q < 8; ++q) a += wr[q] * hsh[lane * 8 + q];
#pragma unroll
    for (int m = 1; m < 64; m <<= 1) a += __shfl_xor(a, m);
    if (lane == 0) dsh[j] = a + bd[j];
  }
  __syncthreads();

  // e-score per s (tid<400)
  float e0 = -3.4e38f;
  if (tid < 400) {
    const float* p = epT + (size_t)b * cM * cS + tid;
    float a0 = 0.f, a1 = 0.f, a2 = 0.f, a3 = 0.f;
#pragma unroll
    for (int j = 0; j < 100; j += 4) {
      a0 += wos[j + 0] * tanh_f(dsh[j + 0] + p[(j + 0) * cS]);
      a1 += wos[j + 1] * tanh_f(dsh[j + 1] + p[(j + 1) * cS]);
      a2 += wos[j + 2] * tanh_f(dsh[j + 2] + p[(j + 2) * cS]);
      a3 += wos[j + 3] * tanh_f(dsh[j + 3] + p[(j + 3) * cS]);
    }
    e0 = bo[0] + ((a0 + a1) + (a2 + a3));
  }
  // softmax over 400 across 8 waves
  float mx = e0;
#pragma unroll
  for (int m = 1; m < 64; m <<= 1) mx = fmaxf(mx, __shfl_xor(mx, m));
  if (lane == 0) red[wid] = mx;
  __syncthreads();
  mx = red[0];
#pragma unroll
  for (int q = 1; q < 8; ++q) mx = fmaxf(mx, red[q]);

  float av = (tid < 400) ? __expf(e0 - mx) : 0.f;
  if (tid < 400) esh[tid] = av;
  float sm = av;
#pragma unroll
  for (int m = 1; m < 64; m <<= 1) sm += __shfl_xor(sm, m);
  if (lane == 0) red[8 + wid] = sm;
  __syncthreads();  // publishes esh + red
  sm = red[8];
#pragma unroll
  for (int q = 1; q < 8; ++q) sm += red[8 + q];
  const float inv = 1.f / sm;

  // context: thread tid owns unit k=tid; 4 loads in flight
  {
    const bf16* sp = sgT + ((size_t)b * cH + tid) * cS;
    float c0 = 0.f, c1 = 0.f, c2 = 0.f, c3 = 0.f;
    for (int s = 0; s < 384; s += 32) {
      bf16x8 v0 = *(const bf16x8*)(sp + s);
      bf16x8 v1 = *(const bf16x8*)(sp + s + 8);
      bf16x8 v2 = *(const bf16x8*)(sp + s + 16);
      bf16x8 v3 = *(const bf16x8*)(sp + s + 24);
#pragma unroll
      for (int j = 0; j < 8; ++j) {
        c0 += esh[s + j] * (float)v0[j];
        c1 += esh[s + 8 + j] * (float)v1[j];
        c2 += esh[s + 16 + j] * (float)v2[j];
        c3 += esh[s + 24 + j] * (float)v3[j];
      }
    }
    {
      bf16x8 v0 = *(const bf16x8*)(sp + 384);
      bf16x8 v1 = *(const bf16x8*)(sp + 392);
#pragma unroll
      for (int j = 0; j < 8; ++j) {
        c0 += esh[384 + j] * (float)v0[j];
        c1 += esh[392 + j] * (float)v1[j];
      }
    }
    xh[(size_t)b * cKcat + tid] = (bf16)(((c0 + c1) + (c2 + c3)) * inv);
  }
  if (tid < 256) {
    const int tok = trg[b * cT + t];
    xh[(size_t)b * cKcat + 512 + tid] = (bf16)emb[(size_t)tok * cE + tid];
  }
  xh[(size_t)b * cKcat + 768 + tid] = hin[b * 512 + tid];
}

// ---------------- decoder fused GRU cell (8 blocks), swizzled Wp ----------------
__global__ __launch_bounds__(256) void gru_k(
    const bf16* __restrict__ xh, const bf16* __restrict__ Wp, const float* __restrict__ bp,
    const float* __restrict__ hin_f, float* __restrict__ hout_f, bf16* __restrict__ hallt) {
  const int tid = threadIdx.x;
  const int lane = tid & 63, wid = tid >> 6;
  const int w = blockIdx.x * 4 + wid;
  const int n0 = w << 6, lr = lane & 15, lh = lane >> 4;
  f32x4 acc[4][4];
#pragma unroll
  for (int i = 0; i < 4; ++i)
#pragma unroll
    for (int j = 0; j < 4; ++j)
#pragma unroll
      for (int r = 0; r < 4; ++r) acc[i][j][r] = 0.f;
#pragma unroll 2
  for (int k0 = 0; k0 < cKcat; k0 += 32) {
    bf16x8 av[4], bw[4];
#pragma unroll
    for (int mt = 0; mt < 4; ++mt)
      av[mt] = *(const bf16x8*)(xh + (size_t)(mt * 16 + lr) * cKcat + k0 + lh * 8);
#pragma unroll
    for (int nt = 0; nt < 4; ++nt)
      bw[nt] = *(const bf16x8*)(Wp + (((size_t)(w * 4 + nt) * 40 + (k0 >> 5)) * 64 + lr * 4 + lh) * 8);
#pragma unroll
    for (int mt = 0; mt < 4; ++mt)
#pragma unroll
      for (int nt = 0; nt < 4; ++nt)
        acc[mt][nt] = __builtin_amdgcn_mfma_f32_16x16x32_bf16(av[mt], bw[nt], acc[mt][nt], 0, 0, 0);
  }
  const int u = (n0 >> 2) + lr;
  const float br = bp[n0 + lr];
  const float bz2 = bp[n0 + 16 + lr];
  const float bi2 = bp[n0 + 32 + lr];
  const float bh2 = bp[n0 + 48 + lr];
#pragma unroll
  for (int mt = 0; mt < 4; ++mt)
#pragma unroll
    for (int r = 0; r < 4; ++r) {
      const int bb = mt * 16 + lh * 4 + r;
      float rr = sigm(acc[mt][0][r] + br);
      float zz = sigm(acc[mt][1][r] + bz2);
      float nn = tanh_f(acc[mt][2][r] + bi2 + rr * (acc[mt][3][r] + bh2));
      float h2v = (1.f - zz) * nn + zz * hin_f[(size_t)bb * cH + u];
      hout_f[(size_t)bb * cH + u] = h2v;
      hallt[(size_t)bb * cH + u] = (bf16)h2v;
    }
}

// ---------------- big logits GEMM, n-major: each block loops all 24 M-tiles ----------------
// Wv fetched from HBM once; re-reads hit the block's own XCD L2.
__global__ __launch_bounds__(256) void biglogits_k(
    const bf16* __restrict__ hall, const bf16* __restrict__ WvS,
    const float* __restrict__ bv, float* __restrict__ partials) {
  const int tid = threadIdx.x;
  const int lane = tid & 63, wid = tid >> 6;
  const int in = blockIdx.x * 4 + wid;
  if (in >= cNTV) return;
  const int lr = lane & 15, lh = lane >> 4;

  bf16x8 bz;
#pragma unroll
  for (int q = 0; q < 8; ++q) bz[q] = (bf16)0.f;

  for (int im = 0; im < cTD; ++im) {
    const int m0 = im << 6;
    f32x4 acc[4][4];
#pragma unroll
    for (int i = 0; i < 4; ++i)
#pragma unroll
      for (int j = 0; j < 4; ++j)
#pragma unroll
        for (int r = 0; r < 4; ++r) acc[i][j][r] = 0.f;

#pragma unroll 2
    for (int k0 = 0; k0 < cH; k0 += 32) {
      bf16x8 av[4], bw[4];
#pragma unroll
      for (int mt = 0; mt < 4; ++mt)
        av[mt] = *(const bf16x8*)(hall + (size_t)(m0 + mt * 16 + lr) * cH + k0 + lh * 8);
#pragma unroll
      for (int nt = 0; nt < 4; ++nt) {
        const int tile = in * 4 + nt;
        bw[nt] = (tile < cVT)
                     ? *(const bf16x8*)(WvS + (((size_t)tile * 16 + (k0 >> 5)) * 64 + lr * 4 + lh) * 8)
                     : bz;
      }
#pragma unroll
      for (int mt = 0; mt < 4; ++mt)
#pragma unroll
        for (int nt = 0; nt < 4; ++nt)
          acc[mt][nt] = __builtin_amdgcn_mfma_f32_16x16x32_bf16(av[mt], bw[nt], acc[mt][nt], 0, 0, 0);
    }

#pragma unroll
    for (int mt = 0; mt < 4; ++mt) {
#pragma unroll
      for (int r = 0; r < 4; ++r) {
        const int m = m0 + mt * 16 + lh * 4 + r;
        float vv[4];
        float mx = -3.4e38f;
#pragma unroll
        for (int nt = 0; nt < 4; ++nt) {
          int n = (in << 6) + nt * 16 + lr;
          float v = (n < cV) ? (acc[mt][nt][r] + bv[n]) : -3.4e38f;
          vv[nt] = v;
          mx = fmaxf(mx, v);
        }
#pragma unroll
        for (int msk = 1; msk < 16; msk <<= 1) mx = fmaxf(mx, __shfl_xor(mx, msk));
        float sm = 0.f;
#pragma unroll
        for (int nt = 0; nt < 4; ++nt) {
          int n = (in << 6) + nt * 16 + lr;
          if (n < cV) sm += __expf(vv[nt] - mx);
        }
#pragma unroll
        for (int msk = 1; msk < 16; msk <<= 1) sm += __shfl_xor(sm, msk);
        if (lr == 0) {
          float* p = partials + ((size_t)m * cNTV + in) * 2;
          p[0] = mx;
          p[1] = sm;
        }
      }
    }
  }
}

// ---------------- per-(step,row) loss ----------------
__global__ __launch_bounds__(64) void rowloss_all_k(
    const float* __restrict__ partials, const bf16* __restrict__ hall,
    const float* __restrict__ Wv, const float* __restrict__ bv,
    const int* __restrict__ trg, float* __restrict__ rnll, float* __restrict__ rw) {
  const int m = blockIdx.x, tid = threadIdx.x;
  const int t = m >> 6, bb = m & 63;
  float mx = -3.4e38f, sm = 0.f;
  const float* pr = partials + (size_t)m * cNTV * 2;
  for (int p = tid; p < cNTV; p += 64) {
    float m2 = pr[p * 2], s2 = pr[p * 2 + 1];
    if (m2 > mx) { sm = sm * __expf(mx - m2) + s2; mx = m2; }
    else sm += s2 * __expf(m2 - mx);
  }
#pragma unroll
  for (int msk = 1; msk < 64; msk <<= 1) {
    float om = __shfl_xor(mx, msk), os = __shfl_xor(sm, msk);
    if (om > mx) { sm = sm * __expf(mx - om) + os; mx = om; }
    else sm += os * __expf(om - mx);
  }
  const int tok = trg[bb * cT + t];
  float dot = 0.f;
  {
    const float* wr = Wv + (size_t)tok * cH + tid * 8;
    const bf16* hr = hall + (size_t)m * cH + tid * 8;
    bf16x8 h8 = *(const bf16x8*)hr;
#pragma unroll
    for (int j = 0; j < 8; ++j) dot += (float)h8[j] * wr[j];
  }
#pragma unroll
  for (int msk = 1; msk < 64; msk <<= 1) dot += __shfl_xor(dot, msk);
  if (tid == 0) {
    float lse = mx + __logf(sm);
    float nll = lse - (dot + bv[tok]);
    float wgt = (tok != cEOS) ? 1.f : 0.f;
    rnll[m] = wgt * nll;
    rw[m] = wgt;
  }
}

__global__ __launch_bounds__(64) void final_loss_k(const float* __restrict__ rnll,
                                                   const float* __restrict__ rw,
                                                   float* __restrict__ out) {
  __shared__ float sl[32];
  const int t = threadIdx.x;
  if (t < cTD) {
    float a = 0.f, d = 0.f;
    for (int b = 0; b < cB; ++b) { a += rnll[t * cB + b]; d += rw[t * cB + b]; }
    sl[t] = a / d;
  }
  __syncthreads();
  if (t == 0) {
    float s = 0.f;
    for (int i = 0; i < cTD; ++i) s += sl[i];
    out[0] = s / (float)cB;
  }
}

// ---------------- host ----------------
extern "C" void kernel_launch(void* const* d_in, const int* in_sizes, int n_in,
                              void* d_out, int out_size, void* d_ws, size_t ws_size,
                              hipStream_t stream) {
  (void)in_sizes; (void)n_in; (void)out_size; (void)ws_size;
  const int* src = (const int*)d_in[0];
  const int* trg = (const int*)d_in[1];
  const float* emb = (const float*)d_in[2];
  const float* Wih_f = (const float*)d_in[3];
  const float* Whh_f = (const float*)d_in[4];
  const float* bih_f = (const float*)d_in[5];
  const float* bhh_f = (const float*)d_in[6];
  const float* Wih_b = (const float*)d_in[7];
  const float* Whh_b = (const float*)d_in[8];
  const float* bih_b = (const float*)d_in[9];
  const float* bhh_b = (const float*)d_in[10];
  const float* W1 = (const float*)d_in[11];
  const float* b1 = (const float*)d_in[12];
  const float* W2 = (const float*)d_in[13];
  const float* b2 = (const float*)d_in[14];
  const float* Wd = (const float*)d_in[15];
  const float* bd = (const float*)d_in[16];
  const float* We = (const float*)d_in[17];
  const float* be = (const float*)d_in[18];
  const float* Wo = (const float*)d_in[19];
  const float* bo = (const float*)d_in[20];
  const float* Wih_c = (const float*)d_in[21];
  const float* Whh_c = (const float*)d_in[22];
  const float* bih_c = (const float*)d_in[23];
  const float* bhh_c = (const float*)d_in[24];
  const float* Wv = (const float*)d_in[25];
  const float* bv = (const float*)d_in[26];
  float* out = (float*)d_out;

  char* ws = (char*)d_ws;
  size_t off = 0;
  auto carve = [&](size_t bytes) -> void* {
    void* p = ws + off;
    off += (bytes + 255) & ~(size_t)255;
    return p;
  };
  bf16* wcat = (bf16*)carve(TOT_W * 2);
  bf16* WvS = wcat + OFF_WV;
  bf16* Wihf_b = wcat + OFF_WIHF;
  bf16* Whhf_b = wcat + OFF_WHHF;
  bf16* Wihb_b = wcat + OFF_WIHB;
  bf16* Whhb_b = wcat + OFF_WHHB;
  bf16* W1_b = wcat + OFF_W1;
  bf16* W2_b = wcat + OFF_W2;
  bf16* We_b = wcat + OFF_WE;
  bf16* Wp_b = (bf16*)carve((size_t)cN4 * cKcat * 2);
  float* bp = (float*)carve((size_t)cN4 * 4);
  bf16* embeds = (bf16*)carve((size_t)cSB * cE * 2);
  float* gi_f = (float*)carve((size_t)cSB * cG2 * 4);
  float* gi_b = (float*)carve((size_t)cSB * cG2 * 4);
  bf16* states = (bf16*)carve((size_t)cSB * cH * 2);
  bf16* statesg = (bf16*)carve((size_t)cSB * cH * 2);
  bf16* statesgT = (bf16*)carve((size_t)cSB * cH * 2);
  bf16* hdec0_bf = (bf16*)carve((size_t)cB * cH * 2);
  float* hdec0_f = (float*)carve((size_t)cB * cH * 4);
  float* hfA = (float*)carve((size_t)cB * cH * 4);
  float* hfB = (float*)carve((size_t)cB * cH * 4);
  float* hw2 = (float*)carve((size_t)cB * cH * 4);
  float* epT = (float*)carve((size_t)cB * cM * cS * 4);
  bf16* xh = (bf16*)carve((size_t)cB * cKcat * 2);
  bf16* hall = (bf16*)carve((size_t)cTD * cB * cH * 2);
  float* partials = (float*)carve((size_t)cTD * cB * cNTV * 2 * 4);
  float* rnll = (float*)carve((size_t)cTD * cB * 4);
  float* rw = (float*)carve((size_t)cTD * cB * 4);

  // 1: merged prep (weight cvt/swizzle + Wp build + embedding gather)
  prep_k<<<dim3(NB_PREP), dim3(256), 0, stream>>>(
      Wv, Wih_f, Whh_f, Wih_b, Whh_b, W1, W2, We, wcat,
      Wih_c, Whh_c, bih_c, bhh_c, Wp_b, bp, src, emb, embeds);
  // 2: both gi GEMMs
  gi2_k<<<dim3(2400), dim3(256), 0, stream>>>(embeds, Wihf_b, bih_f, gi_f,
                                              Wihb_b, bih_b, gi_b);
  // 3: encoder (16 blocks: 2 dirs x 8 batch-chunks)
  enc_rnn_k<<<dim3(16), dim3(512), 0, stream>>>(Whhf_b, Whhb_b, gi_f, gi_b, bhh_f, bhh_b,
                                                hdec0_bf, hdec0_f, states);
  // 4: hw2 = hdec0 @ W2^T + b2
  {
    GArgs ga{hdec0_bf, W2_b, b2, hw2, nullptr, nullptr, nullptr, cB, cH, cH, cH};
    gemm64_k<0><<<dim3(2), dim3(256), 0, stream>>>(ga);
  }
  // 5: sgate
  {
    GArgs ga{states, W1_b, b1, nullptr, statesg, hw2, states, cSB, cH, cH, cH};
    int waves = (cSB / 64) * (cH / 64);
    gemm64_k<1><<<dim3((waves + 3) / 4), dim3(256), 0, stream>>>(ga);
  }
  // 6: encproj (transposed epT) + statesg transpose
  projtransp_k<<<dim3(264), dim3(256), 0, stream>>>(statesg, We_b, be, epT, statesgT);

  // decoder h-chain: launch-based (no fences -> L2 stays warm)
  for (int t = 0; t < cTD; ++t) {
    const bf16* hin_bf = (t == 0) ? hdec0_bf : (hall + (size_t)(t - 1) * cB * cH);
    const float* hin_f = (t == 0) ? hdec0_f : ((t & 1) ? hfA : hfB);
    float* hout_f = (t & 1) ? hfB : hfA;

    attn_k<<<dim3(cB), dim3(512), 0, stream>>>(hin_bf, Wd, bd, Wo, bo, epT, statesgT,
                                               emb, trg, t, xh);
    gru_k<<<dim3(8), dim3(256), 0, stream>>>(xh, Wp_b, bp, hin_f, hout_f,
                                             hall + (size_t)t * cB * cH);
  }

  // all-steps logits (n-major, Wv read once) + loss
  biglogits_k<<<dim3((cNTV + 3) / 4), dim3(256), 0, stream>>>(hall, WvS, bv, partials);
  rowloss_all_k<<<dim3(cTD * cB), dim3(64), 0, stream>>>(partials, hall, Wv, bv, trg, rnll, rw);
  final_loss_k<<<dim3(1), dim3(64), 0, stream>>>(rnll, rw, out);
}

// Round 13
// 3673.965 us; speedup vs baseline: 1.1897x; 1.1897x over previous
//
#include <hip/hip_runtime.h>

typedef __bf16 bf16;
typedef bf16 bf16x2 __attribute__((ext_vector_type(2)));
typedef bf16 bf16x4 __attribute__((ext_vector_type(4)));
typedef bf16 bf16x8 __attribute__((ext_vector_type(8)));
typedef float f32x4 __attribute__((ext_vector_type(4)));

#define DEVFN __device__ __forceinline__

constexpr int cV = 50000, cE = 256, cH = 512, cM = 100, cH2 = 256;
constexpr int cB = 64, cS = 400, cT = 25, cEOS = 2;
constexpr int cSB = cS * cB;          // 25600
constexpr int cG2 = 3 * cH2;          // 768
constexpr int cGP = 772;              // gi LDS row pad
constexpr int cKcat = 1280;           // [c(512) | wemb(256) | h(512)]
constexpr int cN4 = 2048;             // interleaved r,z,inn,hn rows
constexpr int cNTV = (cV + 63) / 64;  // 782
constexpr int cTD = cT - 1;           // 24 decode steps
constexpr int cVT = cV / 16;          // 3125 Wv 16-row tiles

// concatenated bf16 weight cache offsets (elements)
constexpr size_t OFF_WV = 0;
constexpr size_t N_WV = (size_t)cV * cH;
constexpr size_t OFF_WIHF = OFF_WV + N_WV;
constexpr size_t N_WIH = (size_t)cG2 * cE;
constexpr size_t OFF_WHHF = OFF_WIHF + N_WIH;
constexpr size_t N_WHH = (size_t)cG2 * cH2;
constexpr size_t OFF_WIHB = OFF_WHHF + N_WHH;
constexpr size_t OFF_WHHB = OFF_WIHB + N_WIH;
constexpr size_t OFF_W1 = OFF_WHHB + N_WHH;
constexpr size_t N_WSQ = (size_t)cH * cH;
constexpr size_t OFF_W2 = OFF_W1 + N_WSQ;
constexpr size_t OFF_WE = OFF_W2 + N_WSQ;
constexpr size_t N_WE = (size_t)cM * cH;
constexpr size_t TOT_W = OFF_WE + N_WE;

// merged prep grid ranges
constexpr int NB_CVT = (int)(TOT_W / 4 / 256);
constexpr int NB_WP = cN4 * cKcat / 256;
constexpr int NB_GATHER = cSB * cE / 256;
constexpr int NB_PREP = NB_CVT + NB_WP + NB_GATHER;

struct GArgs {
  const bf16* A; const bf16* Bw; const float* bias;
  float* outF; bf16* outBf;
  const float* auxF; const bf16* auxBf;
  int M, N, K, ldo;
};

DEVFN float sigm(float x) { return 1.f / (1.f + __expf(-x)); }
DEVFN float tanh_f(float x) {
  float e2 = __expf(2.f * x);
  return 1.f - 2.f / (e2 + 1.f);
}

DEVFN void gload_lds16(const void* g, void* l) {
  __builtin_amdgcn_global_load_lds(
      (const __attribute__((address_space(1))) void*)g,
      (__attribute__((address_space(3))) void*)l, 16, 0, 0);
}

// ---------------- generic 64x64-per-wave MFMA GEMM: C = A(MxK) * B(NxK)^T ----------------
template <int EPI>
__global__ __launch_bounds__(256) void gemm64_k(GArgs g) {
  const int tid = threadIdx.x;
  const int w = blockIdx.x * 4 + (tid >> 6);
  const int tM = g.M >> 6;
  const int tN = (g.N + 63) >> 6;
  if (w >= tM * tN) return;
  const int im = w % tM, in = w / tM;
  const int m0 = im << 6, n0 = in << 6;
  const int lane = tid & 63, lr = lane & 15, lh = lane >> 4;

  f32x4 acc[4][4];
#pragma unroll
  for (int i = 0; i < 4; ++i)
#pragma unroll
    for (int j = 0; j < 4; ++j)
#pragma unroll
      for (int r = 0; r < 4; ++r) acc[i][j][r] = 0.f;

  bf16x8 bz;
#pragma unroll
  for (int q = 0; q < 8; ++q) bz[q] = (bf16)0.f;

  const int K = g.K;
#pragma unroll 2
  for (int k0 = 0; k0 < K; k0 += 32) {
    bf16x8 av[4], bw[4];
#pragma unroll
    for (int mt = 0; mt < 4; ++mt)
      av[mt] = *(const bf16x8*)(g.A + (size_t)(m0 + mt * 16 + lr) * K + k0 + lh * 8);
#pragma unroll
    for (int nt = 0; nt < 4; ++nt) {
      int row = n0 + nt * 16 + lr;
      bw[nt] = (row < g.N) ? *(const bf16x8*)(g.Bw + (size_t)row * K + k0 + lh * 8) : bz;
    }
#pragma unroll
    for (int mt = 0; mt < 4; ++mt)
#pragma unroll
      for (int nt = 0; nt < 4; ++nt)
        acc[mt][nt] = __builtin_amdgcn_mfma_f32_16x16x32_bf16(av[mt], bw[nt], acc[mt][nt], 0, 0, 0);
  }

#pragma unroll
  for (int mt = 0; mt < 4; ++mt) {
#pragma unroll
    for (int nt = 0; nt < 4; ++nt) {
      const int n = n0 + nt * 16 + lr;
      if (n < g.N) {
        const float bia = g.bias[n];
#pragma unroll
        for (int r = 0; r < 4; ++r) {
          const int m = m0 + mt * 16 + lh * 4 + r;
          float v = acc[mt][nt][r] + bia;
          if constexpr (EPI == 0) {
            g.outF[(size_t)m * g.ldo + n] = v;
          } else {  // EPI==1: sgate epilogue
            float sg = sigm(v + g.auxF[(size_t)(m & 63) * g.ldo + n]);
            float st = (float)g.auxBf[(size_t)m * g.ldo + n];
            g.outBf[(size_t)m * g.ldo + n] = (bf16)(sg * st);
          }
        }
      }
    }
  }
}

// ---------------- merged prep: cvt8(Wv swizzled) + build_wp + gather ----------------
__global__ void prep_k(const float* __restrict__ wv, const float* __restrict__ wihf,
                       const float* __restrict__ whhf, const float* __restrict__ wihb,
                       const float* __restrict__ whhb, const float* __restrict__ w1,
                       const float* __restrict__ w2, const float* __restrict__ we,
                       bf16* __restrict__ dst,
                       const float* __restrict__ Wih_c, const float* __restrict__ Whh_c,
                       const float* __restrict__ bih_c, const float* __restrict__ bhh_c,
                       bf16* __restrict__ Wp, float* __restrict__ bp,
                       const int* __restrict__ src, const float* __restrict__ emb,
                       bf16* __restrict__ embeds) {
  const int blk = blockIdx.x, tid = threadIdx.x;

  if (blk < NB_CVT) {
    size_t i = ((size_t)blk * 256 + tid) * 4;
    if (i >= TOT_W) return;
    if (i < OFF_WIHF) {  // Wv, fragment-swizzled
      float4 v = *(const float4*)(wv + i);
      size_t row = i >> 9, col = i & 511;
      size_t tile = row >> 4, lr = row & 15, kc = col >> 5, lh = (col >> 3) & 3, e = col & 7;
      size_t d = ((tile * 16 + kc) * 64 + lr * 4 + lh) * 8 + e;
      bf16x4 o;
      o[0] = (bf16)v.x; o[1] = (bf16)v.y; o[2] = (bf16)v.z; o[3] = (bf16)v.w;
      *(bf16x4*)(dst + d) = o;
      return;
    }
    const float* s;
    size_t off;
    if (i < OFF_WHHF) { s = wihf; off = OFF_WIHF; }
    else if (i < OFF_WIHB) { s = whhf; off = OFF_WHHF; }
    else if (i < OFF_WHHB) { s = wihb; off = OFF_WIHB; }
    else if (i < OFF_W1) { s = whhb; off = OFF_WHHB; }
    else if (i < OFF_W2) { s = w1; off = OFF_W1; }
    else if (i < OFF_WE) { s = w2; off = OFF_W2; }
    else { s = we; off = OFF_WE; }
    float4 v = *(const float4*)(s + (i - off));
    bf16x4 o;
    o[0] = (bf16)v.x; o[1] = (bf16)v.y; o[2] = (bf16)v.z; o[3] = (bf16)v.w;
    *(bf16x4*)(dst + i) = o;
    return;
  }
  if (blk < NB_CVT + NB_WP) {
    int i = (blk - NB_CVT) * 256 + tid;
    int j = i / cKcat, c = i % cKcat;
    int bi = j >> 6, gg = (j >> 4) & 3, idx = j & 15;
    int u = bi * 16 + idx;
    float v;
    if (gg == 0) v = (c < 768) ? Wih_c[(size_t)u * 768 + c] : Whh_c[(size_t)u * 512 + (c - 768)];
    else if (gg == 1) v = (c < 768) ? Wih_c[(size_t)(512 + u) * 768 + c] : Whh_c[(size_t)(512 + u) * 512 + (c - 768)];
    else if (gg == 2) v = (c < 768) ? Wih_c[(size_t)(1024 + u) * 768 + c] : 0.f;
    else v = (c < 768) ? 0.f : Whh_c[(size_t)(1024 + u) * 512 + (c - 768)];
    {
      size_t tile = (size_t)j >> 4, lr = j & 15, kc = c >> 5, lh = (c >> 3) & 3, e = c & 7;
      Wp[((tile * 40 + kc) * 64 + lr * 4 + lh) * 8 + e] = (bf16)v;
    }
    if (c == 0) {
      float bb;
      if (gg == 0) bb = bih_c[u] + bhh_c[u];
      else if (gg == 1) bb = bih_c[512 + u] + bhh_c[512 + u];
      else if (gg == 2) bb = bih_c[1024 + u];
      else bb = bhh_c[1024 + u];
      bp[j] = bb;
    }
    return;
  }
  {
    int i = (blk - NB_CVT - NB_WP) * 256 + tid;  // over S*B*E
    int e = i & 255;
    int sb = i >> 8;
    int s = sb >> 6, b = sb & 63;
    int tok = src[b * cS + s];
    embeds[i] = (bf16)emb[(size_t)tok * cE + e];
  }
}

// ---------------- both gi GEMMs in one launch ----------------
__global__ __launch_bounds__(256) void gi2_k(const bf16* __restrict__ embeds,
                                             const bf16* __restrict__ WihF,
                                             const float* __restrict__ bihF,
                                             float* __restrict__ giF,
                                             const bf16* __restrict__ WihB,
                                             const float* __restrict__ bihB,
                                             float* __restrict__ giB) {
  int blk = blockIdx.x;
  const bf16* Bw;
  const float* bias;
  float* outF;
  if (blk < 1200) { Bw = WihF; bias = bihF; outF = giF; }
  else { blk -= 1200; Bw = WihB; bias = bihB; outF = giB; }
  const int tid = threadIdx.x;
  const int w = blk * 4 + (tid >> 6);
  const int im = w % 400, in = w / 400;
  const int m0 = im << 6, n0 = in << 6;
  const int lane = tid & 63, lr = lane & 15, lh = lane >> 4;

  f32x4 acc[4][4];
#pragma unroll
  for (int i = 0; i < 4; ++i)
#pragma unroll
    for (int j = 0; j < 4; ++j)
#pragma unroll
      for (int r = 0; r < 4; ++r) acc[i][j][r] = 0.f;

#pragma unroll 2
  for (int k0 = 0; k0 < cE; k0 += 32) {
    bf16x8 av[4], bw[4];
#pragma unroll
    for (int mt = 0; mt < 4; ++mt)
      av[mt] = *(const bf16x8*)(embeds + (size_t)(m0 + mt * 16 + lr) * cE + k0 + lh * 8);
#pragma unroll
    for (int nt = 0; nt < 4; ++nt)
      bw[nt] = *(const bf16x8*)(Bw + (size_t)(n0 + nt * 16 + lr) * cE + k0 + lh * 8);
#pragma unroll
    for (int mt = 0; mt < 4; ++mt)
#pragma unroll
      for (int nt = 0; nt < 4; ++nt)
        acc[mt][nt] = __builtin_amdgcn_mfma_f32_16x16x32_bf16(av[mt], bw[nt], acc[mt][nt], 0, 0, 0);
  }
#pragma unroll
  for (int mt = 0; mt < 4; ++mt)
#pragma unroll
    for (int nt = 0; nt < 4; ++nt) {
      const int n = n0 + nt * 16 + lr;
      const float bia = bias[n];
#pragma unroll
      for (int r = 0; r < 4; ++r) {
        const int m = m0 + mt * 16 + lh * 4 + r;
        outF[(size_t)m * cG2 + n] = acc[mt][nt][r] + bia;
      }
    }
}

// ---------------- encoder GRU v3 (8 blocks, round-3 proven structure) ----------------
__global__ __launch_bounds__(512, 1) void enc_rnn_k(
    const bf16* __restrict__ WhhF, const bf16* __restrict__ WhhB,
    const float* __restrict__ giF, const float* __restrict__ giB,
    const float* __restrict__ bhhF, const float* __restrict__ bhhB,
    bf16* __restrict__ hdec0_bf, float* __restrict__ hdec0_f,
    bf16* __restrict__ states) {
  const int blk = blockIdx.x;
  const int dir = blk >> 2;
  const int bc = blk & 3;
  const bf16* Whh = dir ? WhhB : WhhF;
  const float* gi = dir ? giB : giF;
  const float* bhh = dir ? bhhB : bhhF;

  const int tid = threadIdx.x;
  const int lane = tid & 63, w = tid >> 6;
  const int lr = lane & 15, lh = lane >> 4;
  const int u0 = w * 32;

  bf16x8 Bf[6][8];
  float bh[6];
#pragma unroll
  for (int gg = 0; gg < 3; ++gg)
#pragma unroll
    for (int ut = 0; ut < 2; ++ut) {
      int nbase = gg * 256 + u0 + ut * 16;
#pragma unroll
      for (int kf = 0; kf < 8; ++kf)
        Bf[gg * 2 + ut][kf] = *(const bf16x8*)(Whh + (size_t)(nbase + lr) * 256 + kf * 32 + lh * 8);
      bh[gg * 2 + ut] = bhh[nbase + lr];
    }

  __shared__ float gilds[2][16][cGP];
  __shared__ bf16 hs[2][16][264];

  auto prefetch = [&](int t2) {
    if (t2 >= cS) return;
    const int s2 = dir ? (cS - 1 - t2) : t2;
    const int buf = t2 & 1;
#pragma unroll
    for (int rr2 = 0; rr2 < 2; ++rr2) {
      const int row = w * 2 + rr2;
      const char* srcb = (const char*)(gi + ((size_t)s2 * cB + bc * 16 + row) * cG2);
      char* dstb = (char*)&gilds[buf][row][0];
#pragma unroll
      for (int c = 0; c < 3; ++c)
        gload_lds16(srcb + c * 1024 + lane * 16, dstb + c * 1024);
    }
  };

  float hreg[2][4];
#pragma unroll
  for (int ut = 0; ut < 2; ++ut)
#pragma unroll
    for (int r = 0; r < 4; ++r) hreg[ut][r] = 0.f;

  prefetch(0);
  for (int i = tid; i < 16 * 264; i += 512) ((bf16*)hs[0])[i] = (bf16)0.f;
  __syncthreads();

  for (int t = 0; t < cS; ++t) {
    const int buf = t & 1, nbuf = buf ^ 1;
    prefetch(t + 1);

    bf16x8 av[8];
#pragma unroll
    for (int kf = 0; kf < 8; ++kf)
      av[kf] = *(const bf16x8*)(&hs[buf][lr][kf * 32 + lh * 8]);

    float gir[2][4], giz[2][4], gin[2][4];
#pragma unroll
    for (int ut = 0; ut < 2; ++ut) {
      const int u = u0 + ut * 16 + lr;
#pragma unroll
      for (int r = 0; r < 4; ++r) {
        const int b = lh * 4 + r;
        gir[ut][r] = gilds[buf][b][u];
        giz[ut][r] = gilds[buf][b][256 + u];
        gin[ut][r] = gilds[buf][b][512 + u];
      }
    }

    f32x4 acc[6];
#pragma unroll
    for (int j = 0; j < 6; ++j)
#pragma unroll
      for (int r = 0; r < 4; ++r) acc[j][r] = 0.f;

#pragma unroll
    for (int kf = 0; kf < 8; ++kf)
#pragma unroll
      for (int nt = 0; nt < 6; ++nt)
        acc[nt] = __builtin_amdgcn_mfma_f32_16x16x32_bf16(av[kf], Bf[nt][kf], acc[nt], 0, 0, 0);

#pragma unroll
    for (int ut = 0; ut < 2; ++ut) {
      const int u = u0 + ut * 16 + lr;
#pragma unroll
      for (int r = 0; r < 4; ++r) {
        const int b = lh * 4 + r;
        float rr = sigm(gir[ut][r] + acc[ut][r] + bh[ut]);
        float zz = sigm(giz[ut][r] + acc[2 + ut][r] + bh[2 + ut]);
        float nn = tanh_f(gin[ut][r] + rr * (acc[4 + ut][r] + bh[4 + ut]));
        float hnew = (1.f - zz) * nn + zz * hreg[ut][r];
        hreg[ut][r] = hnew;
        hs[nbuf][b][u] = (bf16)hnew;
      }
    }

    __syncthreads();

    {
      const int s_src = dir ? (cS - 1 - t) : t;
      const int row = tid >> 5, c8 = tid & 31;
      bf16x8 v = *(const bf16x8*)(&hs[nbuf][row][c8 * 8]);
      *(bf16x8*)(states + ((size_t)s_src * cB + bc * 16 + row) * cH + dir * 256 + c8 * 8) = v;
    }
  }

#pragma unroll
  for (int ut = 0; ut < 2; ++ut)
#pragma unroll
    for (int r = 0; r < 4; ++r) {
      const int b = bc * 16 + lh * 4 + r;
      const int col = dir * 256 + u0 + ut * 16 + lr;
      hdec0_f[(size_t)b * cH + col] = hreg[ut][r];
      hdec0_bf[(size_t)b * cH + col] = (bf16)hreg[ut][r];
    }
}

// ---------------- encproj(transposed) + statesg transpose, one launch ----------------
__global__ __launch_bounds__(256) void projtransp_k(const bf16* __restrict__ statesg,
                                                    const bf16* __restrict__ We_b,
                                                    const float* __restrict__ be,
                                                    float* __restrict__ epT,
                                                    bf16* __restrict__ sgT) {
  __shared__ bf16 tile[64][520];
  const int tid = threadIdx.x;
  if (blockIdx.x < 200) {
    const int w = blockIdx.x * 4 + (tid >> 6);
    const int im = w % 400, in = w / 400;
    const int m0 = im << 6, n0 = in << 6;
    const int lane = tid & 63, lr = lane & 15, lh = lane >> 4;
    f32x4 acc[4][4];
#pragma unroll
    for (int i = 0; i < 4; ++i)
#pragma unroll
      for (int j = 0; j < 4; ++j)
#pragma unroll
        for (int r = 0; r < 4; ++r) acc[i][j][r] = 0.f;
    bf16x8 bz;
#pragma unroll
    for (int q = 0; q < 8; ++q) bz[q] = (bf16)0.f;
#pragma unroll 2
    for (int k0 = 0; k0 < cH; k0 += 32) {
      bf16x8 av[4], bw[4];
#pragma unroll
      for (int mt = 0; mt < 4; ++mt)
        av[mt] = *(const bf16x8*)(statesg + (size_t)(m0 + mt * 16 + lr) * cH + k0 + lh * 8);
#pragma unroll
      for (int nt = 0; nt < 4; ++nt) {
        int row = n0 + nt * 16 + lr;
        bw[nt] = (row < cM) ? *(const bf16x8*)(We_b + (size_t)row * cH + k0 + lh * 8) : bz;
      }
#pragma unroll
      for (int mt = 0; mt < 4; ++mt)
#pragma unroll
        for (int nt = 0; nt < 4; ++nt)
          acc[mt][nt] = __builtin_amdgcn_mfma_f32_16x16x32_bf16(av[mt], bw[nt], acc[mt][nt], 0, 0, 0);
    }
#pragma unroll
    for (int mt = 0; mt < 4; ++mt)
#pragma unroll
      for (int nt = 0; nt < 4; ++nt) {
        const int n = n0 + nt * 16 + lr;
        if (n < cM) {
          const float bia = be[n];
#pragma unroll
          for (int r = 0; r < 4; ++r) {
            const int m = m0 + mt * 16 + lh * 4 + r;
            const int bb = m & 63, s = m >> 6;
            epT[((size_t)bb * cM + n) * cS + s] = acc[mt][nt][r] + bia;
          }
        }
      }
    return;
  }
  // transpose: statesg[s][b][k] -> sgT[b][k][s]
  const int b = blockIdx.x - 200;
  for (int s0 = 0; s0 < cS; s0 += 64) {
    __syncthreads();
    for (int c = tid; c < 64 * 64; c += 256) {
      int row = c >> 6, col = c & 63;
      *(bf16x8*)(&tile[row][col * 8]) =
          *(const bf16x8*)(statesg + ((size_t)(s0 + row) * cB + b) * cH + col * 8);
    }
    __syncthreads();
    for (int c = tid; c < 512 * 8; c += 256) {
      int k = c >> 3, sc = c & 7;
      bf16x8 v;
#pragma unroll
      for (int j = 0; j < 8; ++j) v[j] = tile[sc * 8 + j][k];
      *(bf16x8*)(sgT + ((size_t)b * cH + k) * cS + s0 + sc * 8) = v;
    }
  }
}

// ---------------- decoder attention: 64 blocks x 512 threads ----------------
__global__ __launch_bounds__(512) void attn_k(
    const bf16* __restrict__ hin, const float* __restrict__ Wd, const float* __restrict__ bd,
    const float* __restrict__ Wo, const float* __restrict__ bo,
    const float* __restrict__ epT, const bf16* __restrict__ sgT,
    const float* __restrict__ emb, const int* __restrict__ trg, int t,
    bf16* __restrict__ xh) {
  const int b = blockIdx.x, tid = threadIdx.x;
  const int lane = tid & 63, wid = tid >> 6;  // 8 waves
  __shared__ float hsh[512];
  __shared__ float dsh[100];
  __shared__ float esh[400];
  __shared__ float red[32];
  __shared__ float wos[100];

  if (tid < 100) wos[tid] = Wo[tid];
  hsh[tid] = (float)hin[b * 512 + tid];
  __syncthreads();

  // dsh[j] = Wd[j].h + bd[j]; 8 waves strided over j
  for (int j = wid; j < 100; j += 8) {
    const float* wr = Wd + (size_t)j * 512 + lane * 8;
    float a = 0.f;
#pragma unroll
    for (int q = 0; q < 8; ++q) a += wr[q] * hsh[lane * 8 + q];
#pragma unroll
    for (int m = 1; m < 64; m <<= 1) a += __shfl_xor(a, m);
    if (lane == 0) dsh[j] = a + bd[j];
  }
  __syncthreads();

  // e-score per s (tid<400)
  float e0 = -3.4e38f;
  if (tid < 400) {
    const float* p = epT + (size_t)b * cM * cS + tid;
    float a0 = 0.f, a1 = 0.f, a2 = 0.f, a3 = 0.f;
#pragma unroll
    for (int j = 0; j < 100; j += 4) {
      a0 += wos[j + 0] * tanh_f(dsh[j + 0] + p[(j + 0) * cS]);
      a1 += wos[j + 1] * tanh_f(dsh[j + 1] + p[(j + 1) * cS]);
      a2 += wos[j + 2] * tanh_f(dsh[j + 2] + p[(j + 2) * cS]);
      a3 += wos[j + 3] * tanh_f(dsh[j + 3] + p[(j + 3) * cS]);
    }
    e0 = bo[0] + ((a0 + a1) + (a2 + a3));
  }
  // softmax over 400 across 8 waves
  float mx = e0;
#pragma unroll
  for (int m = 1; m < 64; m <<= 1) mx = fmaxf(mx, __shfl_xor(mx, m));
  if (lane == 0) red[wid] = mx;
  __syncthreads();
  mx = red[0];
#pragma unroll
  for (int q = 1; q < 8; ++q) mx = fmaxf(mx, red[q]);

  float av = (tid < 400) ? __expf(e0 - mx) : 0.f;
  if (tid < 400) esh[tid] = av;
  float sm = av;
#pragma unroll
  for (int m = 1; m < 64; m <<= 1) sm += __shfl_xor(sm, m);
  if (lane == 0) red[8 + wid] = sm;
  __syncthreads();  // publishes esh + red
  sm = red[8];
#pragma unroll
  for (int q = 1; q < 8; ++q) sm += red[8 + q];
  const float inv = 1.f / sm;

  // context: thread tid owns unit k=tid; 4 loads in flight
  {
    const bf16* sp = sgT + ((size_t)b * cH + tid) * cS;
    float c0 = 0.f, c1 = 0.f, c2 = 0.f, c3 = 0.f;
    for (int s = 0; s < 384; s += 32) {
      bf16x8 v0 = *(const bf16x8*)(sp + s);
      bf16x8 v1 = *(const bf16x8*)(sp + s + 8);
      bf16x8 v2 = *(const bf16x8*)(sp + s + 16);
      bf16x8 v3 = *(const bf16x8*)(sp + s + 24);
#pragma unroll
      for (int j = 0; j < 8; ++j) {
        c0 += esh[s + j] * (float)v0[j];
        c1 += esh[s + 8 + j] * (float)v1[j];
        c2 += esh[s + 16 + j] * (float)v2[j];
        c3 += esh[s + 24 + j] * (float)v3[j];
      }
    }
    {
      bf16x8 v0 = *(const bf16x8*)(sp + 384);
      bf16x8 v1 = *(const bf16x8*)(sp + 392);
#pragma unroll
      for (int j = 0; j < 8; ++j) {
        c0 += esh[384 + j] * (float)v0[j];
        c1 += esh[392 + j] * (float)v1[j];
      }
    }
    xh[(size_t)b * cKcat + tid] = (bf16)(((c0 + c1) + (c2 + c3)) * inv);
  }
  if (tid < 256) {
    const int tok = trg[b * cT + t];
    xh[(size_t)b * cKcat + 512 + tid] = (bf16)emb[(size_t)tok * cE + tid];
  }
  xh[(size_t)b * cKcat + 768 + tid] = hin[b * 512 + tid];
}

// ---------------- decoder fused GRU cell (8 blocks), swizzled Wp ----------------
__global__ __launch_bounds__(256) void gru_k(
    const bf16* __restrict__ xh, const bf16* __restrict__ Wp, const float* __restrict__ bp,
    const float* __restrict__ hin_f, float* __restrict__ hout_f, bf16* __restrict__ hallt) {
  const int tid = threadIdx.x;
  const int lane = tid & 63, wid = tid >> 6;
  const int w = blockIdx.x * 4 + wid;
  const int n0 = w << 6, lr = lane & 15, lh = lane >> 4;
  f32x4 acc[4][4];
#pragma unroll
  for (int i = 0; i < 4; ++i)
#pragma unroll
    for (int j = 0; j < 4; ++j)
#pragma unroll
      for (int r = 0; r < 4; ++r) acc[i][j][r] = 0.f;
#pragma unroll 2
  for (int k0 = 0; k0 < cKcat; k0 += 32) {
    bf16x8 av[4], bw[4];
#pragma unroll
    for (int mt = 0; mt < 4; ++mt)
      av[mt] = *(const bf16x8*)(xh + (size_t)(mt * 16 + lr) * cKcat + k0 + lh * 8);
#pragma unroll
    for (int nt = 0; nt < 4; ++nt)
      bw[nt] = *(const bf16x8*)(Wp + (((size_t)(w * 4 + nt) * 40 + (k0 >> 5)) * 64 + lr * 4 + lh) * 8);
#pragma unroll
    for (int mt = 0; mt < 4; ++mt)
#pragma unroll
      for (int nt = 0; nt < 4; ++nt)
        acc[mt][nt] = __builtin_amdgcn_mfma_f32_16x16x32_bf16(av[mt], bw[nt], acc[mt][nt], 0, 0, 0);
  }
  const int u = (n0 >> 2) + lr;
  const float br = bp[n0 + lr];
  const float bz2 = bp[n0 + 16 + lr];
  const float bi2 = bp[n0 + 32 + lr];
  const float bh2 = bp[n0 + 48 + lr];
#pragma unroll
  for (int mt = 0; mt < 4; ++mt)
#pragma unroll
    for (int r = 0; r < 4; ++r) {
      const int bb = mt * 16 + lh * 4 + r;
      float rr = sigm(acc[mt][0][r] + br);
      float zz = sigm(acc[mt][1][r] + bz2);
      float nn = tanh_f(acc[mt][2][r] + bi2 + rr * (acc[mt][3][r] + bh2));
      float h2v = (1.f - zz) * nn + zz * hin_f[(size_t)bb * cH + u];
      hout_f[(size_t)bb * cH + u] = h2v;
      hallt[(size_t)bb * cH + u] = (bf16)h2v;
    }
}

// ---------------- big logits GEMM over all 24 steps (m-major, r10 proven) ----------------
__global__ __launch_bounds__(256) void biglogits_k(
    const bf16* __restrict__ hall, const bf16* __restrict__ WvS,
    const float* __restrict__ bv, float* __restrict__ partials) {
  const int tid = threadIdx.x;
  const int lane = tid & 63, wid = tid >> 6;
  const int im = blockIdx.x % cTD;
  const int in = (blockIdx.x / cTD) * 4 + wid;
  if (in >= cNTV) return;
  const int m0 = im << 6, lr = lane & 15, lh = lane >> 4;

  f32x4 acc[4][4];
#pragma unroll
  for (int i = 0; i < 4; ++i)
#pragma unroll
    for (int j = 0; j < 4; ++j)
#pragma unroll
      for (int r = 0; r < 4; ++r) acc[i][j][r] = 0.f;
  bf16x8 bz;
#pragma unroll
  for (int q = 0; q < 8; ++q) bz[q] = (bf16)0.f;

#pragma unroll 2
  for (int k0 = 0; k0 < cH; k0 += 32) {
    bf16x8 av[4], bw[4];
#pragma unroll
    for (int mt = 0; mt < 4; ++mt)
      av[mt] = *(const bf16x8*)(hall + (size_t)(m0 + mt * 16 + lr) * cH + k0 + lh * 8);
#pragma unroll
    for (int nt = 0; nt < 4; ++nt) {
      const int tile = in * 4 + nt;
      bw[nt] = (tile < cVT)
                   ? *(const bf16x8*)(WvS + (((size_t)tile * 16 + (k0 >> 5)) * 64 + lr * 4 + lh) * 8)
                   : bz;
    }
#pragma unroll
    for (int mt = 0; mt < 4; ++mt)
#pragma unroll
      for (int nt = 0; nt < 4; ++nt)
        acc[mt][nt] = __builtin_amdgcn_mfma_f32_16x16x32_bf16(av[mt], bw[nt], acc[mt][nt], 0, 0, 0);
  }

#pragma unroll
  for (int mt = 0; mt < 4; ++mt) {
#pragma unroll
    for (int r = 0; r < 4; ++r) {
      const int m = m0 + mt * 16 + lh * 4 + r;
      float vv[4];
      float mx = -3.4e38f;
#pragma unroll
      for (int nt = 0; nt < 4; ++nt) {
        int n = (in << 6) + nt * 16 + lr;
        float v = (n < cV) ? (acc[mt][nt][r] + bv[n]) : -3.4e38f;
        vv[nt] = v;
        mx = fmaxf(mx, v);
      }
#pragma unroll
      for (int msk = 1; msk < 16; msk <<= 1) mx = fmaxf(mx, __shfl_xor(mx, msk));
      float sm = 0.f;
#pragma unroll
      for (int nt = 0; nt < 4; ++nt) {
        int n = (in << 6) + nt * 16 + lr;
        if (n < cV) sm += __expf(vv[nt] - mx);
      }
#pragma unroll
      for (int msk = 1; msk < 16; msk <<= 1) sm += __shfl_xor(sm, msk);
      if (lr == 0) {
        float* p = partials + ((size_t)m * cNTV + in) * 2;
        p[0] = mx;
        p[1] = sm;
      }
    }
  }
}

// ---------------- per-(step,row) loss ----------------
__global__ __launch_bounds__(64) void rowloss_all_k(
    const float* __restrict__ partials, const bf16* __restrict__ hall,
    const float* __restrict__ Wv, const float* __restrict__ bv,
    const int* __restrict__ trg, float* __restrict__ rnll, float* __restrict__ rw) {
  const int m = blockIdx.x, tid = threadIdx.x;
  const int t = m >> 6, bb = m & 63;
  float mx = -3.4e38f, sm = 0.f;
  const float* pr = partials + (size_t)m * cNTV * 2;
  for (int p = tid; p < cNTV; p += 64) {
    float m2 = pr[p * 2], s2 = pr[p * 2 + 1];
    if (m2 > mx) { sm = sm * __expf(mx - m2) + s2; mx = m2; }
    else sm += s2 * __expf(m2 - mx);
  }
#pragma unroll
  for (int msk = 1; msk < 64; msk <<= 1) {
    float om = __shfl_xor(mx, msk), os = __shfl_xor(sm, msk);
    if (om > mx) { sm = sm * __expf(mx - om) + os; mx = om; }
    else sm += os * __expf(om - mx);
  }
  const int tok = trg[bb * cT + t];
  float dot = 0.f;
  {
    const float* wr = Wv + (size_t)tok * cH + tid * 8;
    const bf16* hr = hall + (size_t)m * cH + tid * 8;
    bf16x8 h8 = *(const bf16x8*)hr;
#pragma unroll
    for (int j = 0; j < 8; ++j) dot += (float)h8[j] * wr[j];
  }
#pragma unroll
  for (int msk = 1; msk < 64; msk <<= 1) dot += __shfl_xor(dot, msk);
  if (tid == 0) {
    float lse = mx + __logf(sm);
    float nll = lse - (dot + bv[tok]);
    float wgt = (tok != cEOS) ? 1.f : 0.f;
    rnll[m] = wgt * nll;
    rw[m] = wgt;
  }
}

__global__ __launch_bounds__(64) void final_loss_k(const float* __restrict__ rnll,
                                                   const float* __restrict__ rw,
                                                   float* __restrict__ out) {
  __shared__ float sl[32];
  const int t = threadIdx.x;
  if (t < cTD) {
    float a = 0.f, d = 0.f;
    for (int b = 0; b < cB; ++b) { a += rnll[t * cB + b]; d += rw[t * cB + b]; }
    sl[t] = a / d;
  }
  __syncthreads();
  if (t == 0) {
    float s = 0.f;
    for (int i = 0; i < cTD; ++i) s += sl[i];
    out[0] = s / (float)cB;
  }
}

// ---------------- host ----------------
extern "C" void kernel_launch(void* const* d_in, const int* in_sizes, int n_in,
                              void* d_out, int out_size, void* d_ws, size_t ws_size,
                              hipStream_t stream) {
  (void)in_sizes; (void)n_in; (void)out_size; (void)ws_size;
  const int* src = (const int*)d_in[0];
  const int* trg = (const int*)d_in[1];
  const float* emb = (const float*)d_in[2];
  const float* Wih_f = (const float*)d_in[3];
  const float* Whh_f = (const float*)d_in[4];
  const float* bih_f = (const float*)d_in[5];
  const float* bhh_f = (const float*)d_in[6];
  const float* Wih_b = (const float*)d_in[7];
  const float* Whh_b = (const float*)d_in[8];
  const float* bih_b = (const float*)d_in[9];
  const float* bhh_b = (const float*)d_in[10];
  const float* W1 = (const float*)d_in[11];
  const float* b1 = (const float*)d_in[12];
  const float* W2 = (const float*)d_in[13];
  const float* b2 = (const float*)d_in[14];
  const float* Wd = (const float*)d_in[15];
  const float* bd = (const float*)d_in[16];
  const float* We = (const float*)d_in[17];
  const float* be = (const float*)d_in[18];
  const float* Wo = (const float*)d_in[19];
  const float* bo = (const float*)d_in[20];
  const float* Wih_c = (const float*)d_in[21];
  const float* Whh_c = (const float*)d_in[22];
  const float* bih_c = (const float*)d_in[23];
  const float* bhh_c = (const float*)d_in[24];
  const float* Wv = (const float*)d_in[25];
  const float* bv = (const float*)d_in[26];
  float* out = (float*)d_out;

  char* ws = (char*)d_ws;
  size_t off = 0;
  auto carve = [&](size_t bytes) -> void* {
    void* p = ws + off;
    off += (bytes + 255) & ~(size_t)255;
    return p;
  };
  bf16* wcat = (bf16*)carve(TOT_W * 2);
  bf16* WvS = wcat + OFF_WV;
  bf16* Wihf_b = wcat + OFF_WIHF;
  bf16* Whhf_b = wcat + OFF_WHHF;
  bf16* Wihb_b = wcat + OFF_WIHB;
  bf16* Whhb_b = wcat + OFF_WHHB;
  bf16* W1_b = wcat + OFF_W1;
  bf16* W2_b = wcat + OFF_W2;
  bf16* We_b = wcat + OFF_WE;
  bf16* Wp_b = (bf16*)carve((size_t)cN4 * cKcat * 2);
  float* bp = (float*)carve((size_t)cN4 * 4);
  bf16* embeds = (bf16*)carve((size_t)cSB * cE * 2);
  float* gi_f = (float*)carve((size_t)cSB * cG2 * 4);
  float* gi_b = (float*)carve((size_t)cSB * cG2 * 4);
  bf16* states = (bf16*)carve((size_t)cSB * cH * 2);
  bf16* statesg = (bf16*)carve((size_t)cSB * cH * 2);
  bf16* statesgT = (bf16*)carve((size_t)cSB * cH * 2);
  bf16* hdec0_bf = (bf16*)carve((size_t)cB * cH * 2);
  float* hdec0_f = (float*)carve((size_t)cB * cH * 4);
  float* hfA = (float*)carve((size_t)cB * cH * 4);
  float* hfB = (float*)carve((size_t)cB * cH * 4);
  float* hw2 = (float*)carve((size_t)cB * cH * 4);
  float* epT = (float*)carve((size_t)cB * cM * cS * 4);
  bf16* xh = (bf16*)carve((size_t)cB * cKcat * 2);
  bf16* hall = (bf16*)carve((size_t)cTD * cB * cH * 2);
  float* partials = (float*)carve((size_t)cTD * cB * cNTV * 2 * 4);
  float* rnll = (float*)carve((size_t)cTD * cB * 4);
  float* rw = (float*)carve((size_t)cTD * cB * 4);

  // 1: merged prep (weight cvt/swizzle + Wp build + embedding gather)
  prep_k<<<dim3(NB_PREP), dim3(256), 0, stream>>>(
      Wv, Wih_f, Whh_f, Wih_b, Whh_b, W1, W2, We, wcat,
      Wih_c, Whh_c, bih_c, bhh_c, Wp_b, bp, src, emb, embeds);
  // 2: both gi GEMMs
  gi2_k<<<dim3(2400), dim3(256), 0, stream>>>(embeds, Wihf_b, bih_f, gi_f,
                                              Wihb_b, bih_b, gi_b);
  // 3: encoder (8 blocks, proven)
  enc_rnn_k<<<dim3(8), dim3(512), 0, stream>>>(Whhf_b, Whhb_b, gi_f, gi_b, bhh_f, bhh_b,
                                               hdec0_bf, hdec0_f, states);
  // 4: hw2 = hdec0 @ W2^T + b2
  {
    GArgs ga{hdec0_bf, W2_b, b2, hw2, nullptr, nullptr, nullptr, cB, cH, cH, cH};
    gemm64_k<0><<<dim3(2), dim3(256), 0, stream>>>(ga);
  }
  // 5: sgate
  {
    GArgs ga{states, W1_b, b1, nullptr, statesg, hw2, states, cSB, cH, cH, cH};
    int waves = (cSB / 64) * (cH / 64);
    gemm64_k<1><<<dim3((waves + 3) / 4), dim3(256), 0, stream>>>(ga);
  }
  // 6: encproj (transposed epT) + statesg transpose
  projtransp_k<<<dim3(264), dim3(256), 0, stream>>>(statesg, We_b, be, epT, statesgT);

  // decoder h-chain: launch-based (no fences -> L2 stays warm)
  for (int t = 0; t < cTD; ++t) {
    const bf16* hin_bf = (t == 0) ? hdec0_bf : (hall + (size_t)(t - 1) * cB * cH);
    const float* hin_f = (t == 0) ? hdec0_f : ((t & 1) ? hfA : hfB);
    float* hout_f = (t & 1) ? hfB : hfA;

    attn_k<<<dim3(cB), dim3(512), 0, stream>>>(hin_bf, Wd, bd, Wo, bo, epT, statesgT,
                                               emb, trg, t, xh);
    gru_k<<<dim3(8), dim3(256), 0, stream>>>(xh, Wp_b, bp, hin_f, hout_f,
                                             hall + (size_t)t * cB * cH);
  }

  // all-steps logits + loss
  biglogits_k<<<dim3(cTD * ((cNTV + 3) / 4)), dim3(256), 0, stream>>>(hall, WvS, bv, partials);
  rowloss_all_k<<<dim3(cTD * cB), dim3(64), 0, stream>>>(partials, hall, Wv, bv, trg, rnll, rw);
  final_loss_k<<<dim3(1), dim3(64), 0, stream>>>(rnll, rw, out);
}